// Round 10
// baseline (48.050 us; speedup 1.0000x reference)
//
#include <hip/hip_runtime.h>

#define HH 256
#define WW 256
#define CC 64
#define NG 8
#define NE 32
#define PX 32           // pixels per block; 8 per wave
#define THRESH 15.0f

typedef float f32x4 __attribute__((ext_vector_type(4)));

// out layout: feats (8,256,256,65) floats, then mask (8,256,256) floats
#define FEATS_ELEMS ((size_t)NG * HH * WW * 65)

// img tile: row r = yy*33 + x ; yy in {0,1} -> img rows v-1,v ; x in [0,33) -> cols u0-1..u0+31
// addr = r*65 + c. 66*65 = 4290 floats. t tile aliases rows 0..31 (t(p,c)=p*65+c).
#define IMG_ELEMS (CC * 2 * 33)   // 4224 loaded elements

__global__ __launch_bounds__(256, 6) void fused_sparse_encoder(
    const float* __restrict__ img,    // (64,256,256)
    const float* __restrict__ edges,  // (8,32,4)
    float* __restrict__ out)
{
#pragma clang fp contract(off)
    __shared__ __align__(16) float s_buf[66 * 65];   // 17.16 KB, img tile then t tile
    __shared__ float4 s_k1[NG * NE];                 // e0v, e0u, dn0, dn1
    __shared__ float2 s_k2[NG * NE];                 // e1v, e1u
    __shared__ float  s_k3[NG * NE];                 // Lm
    __shared__ float  s_m[NG * PX];
    __shared__ float  s_p[NG * PX];

    const int tid  = threadIdx.x;
    const int wv   = tid >> 6;
    const int lane = tid & 63;
    const int u0   = blockIdx.x * PX;
    const int v    = blockIdx.y;

    // ---- Phase A: per-edge precompute (256 threads = 256 edges)
    {
        const float4 e4 = reinterpret_cast<const float4*>(edges)[tid];
        const float e0v = e4.x * 256.0f;
        const float e0u = e4.y * 256.0f;
        const float e1v = e4.z * 256.0f;
        const float e1u = e4.w * 256.0f;
        const float d0 = e1v - e0v;
        const float d1 = e1u - e0u;
        const float L  = __fsqrt_rn(d0 * d0 + d1 * d1);
        const float Lm = fmaxf(L, 1e-4f);
        s_k1[tid] = make_float4(e0v, e0u, __fdiv_rn(d0, Lm), __fdiv_rn(d1, Lm));
        s_k2[tid] = make_float2(e1v, e1u);
        s_k3[tid] = Lm;
    }
    __syncthreads();

    // ---- Phase C-issue: img tile loads into registers (in flight during Phase B)
    float cbuf[17];
    #pragma unroll
    for (int t = 0; t < 17; ++t) {
        const int i = tid + t * 256;
        float val = 0.0f;
        if (i < IMG_ELEMS) {
            const int c  = i / 66;
            const int r  = i - c * 66;
            const int yy = r / 33;
            const int x  = r - yy * 33;
            const int gy = v - 1 + yy;
            const int gx = u0 - 1 + x;
            if (gy >= 0 && gx >= 0) {        // gy<=255, gx<=255 always
                val = img[((size_t)c * HH + gy) * WW + gx];
            }
        }
        cbuf[t] = val;
    }

    // ---- Phase B: mask + pinfo, one (g,px) per thread; result kept in regs,
    //      mask/pinfo shared via LDS, global mask store DEFERRED to kernel end.
    float mv_reg, pf_reg;
    const int b_px = tid & (PX - 1);
    const int b_g  = tid >> 5;
    {
        const float U = (float)(u0 + b_px);
        const float V = (float)v;
        float sm = 0.0f, cnt = 0.0f;
        bool any = false;
        for (int e = 0; e < NE; ++e) {
            const int idx = b_g * NE + e;
            const float4 k1 = s_k1[idx];
            const float2 k2 = s_k2[idx];
            const float  Lm = s_k3[idx];
            const float diff0 = V - k1.x;
            const float diff1 = U - k1.y;
            const float ndv = diff0 * k1.w - diff1 * k1.z;
            const float ddn = diff0 * k1.z + diff1 * k1.w;
            const float dd  = __fdiv_rn(ddn, Lm);
            const float r0sq = diff0 * diff0 + diff1 * diff1;
            const float f0 = V - k2.x;
            const float f1 = U - k2.y;
            const float r1sq = f0 * f0 + f1 * f1;
            const bool m = ((fabsf(ndv) <= THRESH) && (dd <= 1.0f) && (dd >= 0.0f))
                           || (r0sq <= 225.0f) || (r1sq <= 225.0f);
            if (m) {
                any = true;
                sm += fminf(dd, 1.0f - dd);
                cnt += 1.0f;
            }
        }
        pf_reg = __fdiv_rn(sm, fmaxf(cnt, 1e-4f));
        mv_reg = any ? 1.0f : 0.0f;
        s_m[b_g * PX + b_px] = mv_reg;
        s_p[b_g * PX + b_px] = pf_reg;
    }

    // ---- Phase C-commit: registers -> LDS img tile
    #pragma unroll
    for (int t = 0; t < 17; ++t) {
        const int i = tid + t * 256;
        if (i < IMG_ELEMS) {
            const int c  = i / 66;
            const int r  = i - c * 66;
            const int yy = r / 33;
            const int x  = r - yy * 33;
            s_buf[(yy * 33 + x) * 65 + c] = cbuf[t];
        }
    }
    __syncthreads();   // barrier 1: tile + s_m/s_p visible

    // ---- Phase D1: 2x2 box sample; wave wv owns pixels [8wv, 8wv+8), lane = channel
    float sreg[8];
    #pragma unroll
    for (int i = 0; i < 8; ++i) {
        const int p = wv * 8 + i;
        sreg[i] = s_buf[(p) * 65 + lane] * 0.25f
                + s_buf[(p + 1) * 65 + lane] * 0.25f
                + s_buf[(33 + p) * 65 + lane] * 0.25f
                + s_buf[(34 + p) * 65 + lane] * 0.25f;
    }
    __syncthreads();   // barrier 2: all samples read before t overwrites img rows

    // ---- Phase D2: transpose own 8 rows into t region (rows 8wv..8wv+7)
    #pragma unroll
    for (int i = 0; i < 8; ++i) {
        s_buf[(wv * 8 + i) * 65 + lane] = sreg[i];
    }
    // NO barrier: Phase E reads only this wave's own t rows (in-wave lgkmcnt orders)

    // ---- Phase E: wave streams its own record-aligned slice: 520 floats x 8 g.
    {
        const int slice = wv * 8;                       // first pixel of slice
        const float* tbase = &s_buf[slice * 65];
        const float* msk = &s_m[slice];
        const float* pin = &s_p[slice];

        // part 0/1: q = lane, lane+64 (full waves); part 2: q = 128+lane, lanes 0..1
        int  f_[3], p0_[3], b_[3];
        f32x4 tv_[3];
        #pragma unroll
        for (int part = 0; part < 3; ++part) {
            const int q = lane + part * 64;
            const bool on = (part < 2) || (lane < 2);
            const int f  = q * 4;
            const int p0 = (int)((unsigned)f / 65u);
            f_[part] = f; p0_[part] = p0; b_[part] = (p0 + 1) * 65 - f;
            if (on) tv_[part] = *reinterpret_cast<const f32x4*>(&tbase[f]);
        }

        for (int g = 0; g < NG; ++g) {
            float* gout = out + (((size_t)g * HH + v) * WW + u0 + slice) * 65;
            const float* mg = msk + g * PX;
            const float* pg = pin + g * PX;
            #pragma unroll
            for (int part = 0; part < 3; ++part) {
                if ((part < 2) || (lane < 2)) {
                    const int f  = f_[part];
                    const int p0 = p0_[part];
                    const int b  = b_[part];
                    const f32x4 tv = tv_[part];
                    const float m0 = mg[p0];
                    const float m1 = mg[(b < 4) ? (p0 + 1) : p0];
                    const float pi = pg[p0];
                    f32x4 r;
                    r.x = ((b == 1) ? pi : tv.x) * ((0 < b) ? m0 : m1);
                    r.y = ((b == 2) ? pi : tv.y) * ((1 < b) ? m0 : m1);
                    r.z = ((b == 3) ? pi : tv.z) * ((2 < b) ? m0 : m1);
                    r.w = ((b == 4) ? pi : tv.w) * ((3 < b) ? m0 : m1);
                    __builtin_nontemporal_store(r, reinterpret_cast<f32x4*>(&gout[f]));
                }
            }
        }
    }

    // ---- deferred mask store (no barrier crossed any pending store)
    out[FEATS_ELEMS + ((size_t)b_g * HH + v) * WW + (u0 + b_px)] = mv_reg;
}

extern "C" void kernel_launch(void* const* d_in, const int* in_sizes, int n_in,
                              void* d_out, int out_size, void* d_ws, size_t ws_size,
                              hipStream_t stream) {
    const float* img   = (const float*)d_in[0];
    const float* edges = (const float*)d_in[1];
    float* out = (float*)d_out;
    dim3 grid(WW / PX, HH);
    fused_sparse_encoder<<<grid, 256, 0, stream>>>(img, edges, out);
}

// Round 11
// 41.286 us; speedup vs baseline: 1.1638x; 1.1638x over previous
//
#include <hip/hip_runtime.h>

#define HH 256
#define WW 256
#define CC 64
#define NG 8
#define NE 32
#define PX 32           // pixels per block
#define THRESH 15.0f

typedef float f32x4 __attribute__((ext_vector_type(4)));
typedef float f32x2 __attribute__((ext_vector_type(2)));

// out layout: feats (8,256,256,65) floats, then mask (8,256,256) floats
#define FEATS_ELEMS ((size_t)NG * HH * WW * 65)

// img tile in LDS: row r = yy*33 + x ; yy in {0,1} -> img rows v-1,v ; x in [0,33) -> cols u0-1..u0+31
// addr = r*65 + c ; 66*65 = 4290 floats. t tile aliases rows 0..31: t(p,c) = p*65 + c.
// Global loads are float2 over 34 cols (u0-2 .. u0+31): 17 float2 per (c,yy) row,
// 64ch*2rows*17 = 2176 float2 -> 8.5 per thread (cbuf[9], last half-tail guarded).
// Loaded x2-index x2 in [0,17): covers cols u0-2+2*x2, u0-1+2*x2 -> LDS x = 2*x2-1, 2*x2.
#define LD2_PER_ROW 17
#define LD2_ELEMS (CC * 2 * LD2_PER_ROW)   // 2176

__global__ __launch_bounds__(256, 6) void fused_sparse_encoder(
    const float* __restrict__ img,    // (64,256,256)
    const float* __restrict__ edges,  // (8,32,4)
    float* __restrict__ out)
{
#pragma clang fp contract(off)
    __shared__ __align__(16) float s_buf[66 * 65];   // 17.16 KB, img tile then t tile
    __shared__ float4 s_k1[NG * NE];                 // e0v, e0u, dn0, dn1
    __shared__ float4 s_k2[NG * NE];                 // e1v, e1u, Lm, pad
    __shared__ float  s_m[NG * PX];
    __shared__ float  s_p[NG * PX];

    const int tid  = threadIdx.x;
    const int wv   = tid >> 6;
    const int lane = tid & 63;
    const int u0   = blockIdx.x * PX;
    const int v    = blockIdx.y;

    // ---- Phase A: per-edge precompute (256 threads = 256 edges)
    {
        const float4 e4 = reinterpret_cast<const float4*>(edges)[tid];
        const float e0v = e4.x * 256.0f;
        const float e0u = e4.y * 256.0f;
        const float e1v = e4.z * 256.0f;
        const float e1u = e4.w * 256.0f;
        const float d0 = e1v - e0v;
        const float d1 = e1u - e0u;
        const float L  = __fsqrt_rn(d0 * d0 + d1 * d1);
        const float Lm = fmaxf(L, 1e-4f);
        s_k1[tid] = make_float4(e0v, e0u, __fdiv_rn(d0, Lm), __fdiv_rn(d1, Lm));
        s_k2[tid] = make_float4(e1v, e1u, Lm, 0.0f);
    }
    __syncthreads();

    // ---- Phase C-issue: img tile float2 loads into registers (fly during Phase B)
    f32x2 cbuf[9];
    #pragma unroll
    for (int t = 0; t < 9; ++t) {
        const int i = tid + t * 256;
        f32x2 val = {0.0f, 0.0f};
        if (i < LD2_ELEMS) {
            const int c  = i / (2 * LD2_PER_ROW);
            const int r  = i - c * (2 * LD2_PER_ROW);
            const int yy = (r >= LD2_PER_ROW) ? 1 : 0;
            const int x2 = r - yy * LD2_PER_ROW;
            const int gy = v - 1 + yy;
            const int gx = u0 - 2 + 2 * x2;          // even, 8B aligned
            if (gy >= 0 && gx >= 0) {                // gy<=255, gx+1<=255 always
                val = *reinterpret_cast<const f32x2*>(&img[((size_t)c * HH + gy) * WW + gx]);
            } else if (gy >= 0 && gx == -2) {
                val.y = 0.0f; val.x = 0.0f;          // both cols out of range (gx=-2,-1)
            }
        }
        cbuf[t] = val;
    }

    // ---- Phase B: mask + pinfo, one (g,px) per thread (overlaps load latency)
    {
        const int px = tid & (PX - 1);
        const int g  = tid >> 5;
        const float U = (float)(u0 + px);
        const float V = (float)v;
        float sm = 0.0f, cnt = 0.0f;
        bool any = false;
        for (int e = 0; e < NE; ++e) {
            const int idx = g * NE + e;
            const float4 k1 = s_k1[idx];
            const float4 k2 = s_k2[idx];
            const float diff0 = V - k1.x;
            const float diff1 = U - k1.y;
            const float ndv = diff0 * k1.w - diff1 * k1.z;
            const float ddn = diff0 * k1.z + diff1 * k1.w;
            const float dd  = __fdiv_rn(ddn, k2.z);
            const float r0sq = diff0 * diff0 + diff1 * diff1;
            const float f0 = V - k2.x;
            const float f1 = U - k2.y;
            const float r1sq = f0 * f0 + f1 * f1;
            const bool m = ((fabsf(ndv) <= THRESH) && (dd <= 1.0f) && (dd >= 0.0f))
                           || (r0sq <= 225.0f) || (r1sq <= 225.0f);
            if (m) {
                any = true;
                sm += fminf(dd, 1.0f - dd);
                cnt += 1.0f;
            }
        }
        const float pf = __fdiv_rn(sm, fmaxf(cnt, 1e-4f));
        const float mv = any ? 1.0f : 0.0f;
        s_m[g * PX + px] = mv;
        s_p[g * PX + px] = pf;
        out[FEATS_ELEMS + ((size_t)g * HH + v) * WW + (u0 + px)] = mv;
    }

    // ---- Phase C-commit: registers -> LDS img tile (x = 2*x2-1, 2*x2; skip x=-1)
    #pragma unroll
    for (int t = 0; t < 9; ++t) {
        const int i = tid + t * 256;
        if (i < LD2_ELEMS) {
            const int c  = i / (2 * LD2_PER_ROW);
            const int r  = i - c * (2 * LD2_PER_ROW);
            const int yy = (r >= LD2_PER_ROW) ? 1 : 0;
            const int x2 = r - yy * LD2_PER_ROW;
            const int xb = 2 * x2 - 1;               // LDS col of val.x
            const int rowb = yy * 33;
            if (xb >= 0) s_buf[(rowb + xb) * 65 + c] = cbuf[t].x;
            s_buf[(rowb + xb + 1) * 65 + c] = cbuf[t].y;
        }
    }
    __syncthreads();   // barrier 1: tile + s_m/s_p visible

    // ---- Phase D1: 2x2 box sample; wave wv owns pixels [8wv, 8wv+8), lane = channel
    float sreg[8];
    #pragma unroll
    for (int i = 0; i < 8; ++i) {
        const int p = wv * 8 + i;
        sreg[i] = s_buf[(p) * 65 + lane] * 0.25f
                + s_buf[(p + 1) * 65 + lane] * 0.25f
                + s_buf[(33 + p) * 65 + lane] * 0.25f
                + s_buf[(34 + p) * 65 + lane] * 0.25f;
    }
    __syncthreads();   // barrier 2: all samples read before t overwrites img rows

    // ---- Phase D2: transpose into t region (rows 0..31 of s_buf)
    #pragma unroll
    for (int i = 0; i < 8; ++i) {
        s_buf[(wv * 8 + i) * 65 + lane] = sreg[i];
    }
    __syncthreads();   // barrier 3: t tile complete

    // ---- Phase E: hoisted per-thread quad params + t reads (g-invariant), then 8 store passes
    int  e_f[3], e_p0[3], e_b[3];
    bool e_on[3];
    f32x4 e_tv[3];
    #pragma unroll
    for (int k = 0; k < 3; ++k) {
        const int q = tid + k * 256;
        e_on[k] = (q < 520);
        const int f  = q * 4;
        const int p0 = (int)((unsigned)f / 65u);
        e_f[k] = f; e_p0[k] = p0; e_b[k] = (p0 + 1) * 65 - f;
        if (e_on[k]) e_tv[k] = *reinterpret_cast<const f32x4*>(&s_buf[f]);
    }

    for (int g = 0; g < NG; ++g) {
        float* gout = out + (((size_t)g * HH + v) * WW + u0) * 65;
        const float* mg = &s_m[g * PX];
        const float* pg = &s_p[g * PX];
        #pragma unroll
        for (int k = 0; k < 3; ++k) {
            if (e_on[k]) {
                const int f  = e_f[k];
                const int p0 = e_p0[k];
                const int b  = e_b[k];
                const f32x4 tv = e_tv[k];
                const float m0 = mg[p0];
                const float m1 = mg[(b < 4) ? (p0 + 1) : p0];
                const float pi = pg[p0];
                f32x4 r;
                r.x = ((b == 1) ? pi : tv.x) * ((0 < b) ? m0 : m1);
                r.y = ((b == 2) ? pi : tv.y) * ((1 < b) ? m0 : m1);
                r.z = ((b == 3) ? pi : tv.z) * ((2 < b) ? m0 : m1);
                r.w = ((b == 4) ? pi : tv.w) * ((3 < b) ? m0 : m1);
                __builtin_nontemporal_store(r, reinterpret_cast<f32x4*>(&gout[f]));
            }
        }
    }
}

extern "C" void kernel_launch(void* const* d_in, const int* in_sizes, int n_in,
                              void* d_out, int out_size, void* d_ws, size_t ws_size,
                              hipStream_t stream) {
    const float* img   = (const float*)d_in[0];
    const float* edges = (const float*)d_in[1];
    float* out = (float*)d_out;
    dim3 grid(WW / PX, HH);
    fused_sparse_encoder<<<grid, 256, 0, stream>>>(img, edges, out);
}